// Round 5
// baseline (1342.636 us; speedup 1.0000x reference)
//
#include <hip/hip_runtime.h>

// (V, D, H, L, E) = (50000, 128, 128, 4, 160000)
#define V_NODES 50000
#define NEDGE   160000

typedef __bf16 bf16;
typedef __attribute__((ext_vector_type(8))) __bf16 bf16x8;
typedef __attribute__((ext_vector_type(4))) __bf16 bf16x4;
typedef __attribute__((ext_vector_type(4))) float  f32x4;

__device__ __forceinline__ int clampV(int n) {
  unsigned u = (unsigned)n;
  return (int)(u < (unsigned)V_NODES ? u : (unsigned)(V_NODES - 1));
}

// packed bf16x2 atomic add (gfx90a+/gfx950): 2 values per fabric op
__device__ __forceinline__ void pk_atomic_bf16(bf16* addr, float lo, float hi) {
  bf16 l = (bf16)lo, h = (bf16)hi;
  unsigned int packed = ((unsigned int)__builtin_bit_cast(unsigned short, h) << 16)
                      | (unsigned int)__builtin_bit_cast(unsigned short, l);
  asm volatile("global_atomic_pk_add_bf16 %0, %1, off"
               :: "v"(addr), "v"(packed) : "memory");
}

// ---------------- prep kernels: fp32 -> bf16 (weights transposed) ----------

__global__ __launch_bounds__(256) void prep_emb_k(const float* __restrict__ in,
                                                  bf16* __restrict__ out) {
  int i = blockIdx.x * 256 + threadIdx.x;           // one thread per 4 elems
  float4 v = ((const float4*)in)[i];
  bf16x4 o = {(bf16)v.x, (bf16)v.y, (bf16)v.z, (bf16)v.w};
  *(bf16x4*)(out + (size_t)i * 4) = o;
}

// W1: (4,2,256,128) -> W1T[g][n(128)][k(256)] bf16   (A-operand for h^T GEMM)
__global__ __launch_bounds__(256) void prep_w1_k(const float* __restrict__ in,
                                                 bf16* __restrict__ out) {
  int idx = blockIdx.x * 256 + threadIdx.x;         // 262144 total
  int n = idx & 127, k = (idx >> 7) & 255, g = idx >> 15;
  out[(((g << 7) + n) << 8) + k] = (bf16)in[idx];
}

// W2: (4,2,128,128) -> W2T[g][n(128)][k(128)] bf16   (B-operand for final GEMM)
__global__ __launch_bounds__(256) void prep_w2_k(const float* __restrict__ in,
                                                 bf16* __restrict__ out) {
  int idx = blockIdx.x * 256 + threadIdx.x;         // 131072 total
  int n = idx & 127, k = (idx >> 7) & 127, g = idx >> 14;
  out[(((g << 7) + n) << 7) + k] = (bf16)in[idx];
}

__global__ __launch_bounds__(256) void relu_k(float* __restrict__ out) {
  int i = blockIdx.x * 256 + threadIdx.x;           // one thread per 4 elems
  float4 v = ((float4*)out)[i];
  v.x = fmaxf(v.x, 0.f); v.y = fmaxf(v.y, 0.f);
  v.z = fmaxf(v.z, 0.f); v.w = fmaxf(v.w, 0.f);
  ((float4*)out)[i] = v;
}

// ---------------- main path: h-scatter edge kernel -------------------------
// Computes h^T = W1^T @ raw^T per (l,ep) group; each wave: ep = w>>1,
// dims-half dh = w&1 (64 hidden dims), 16 edges/tile. W1 A-fragments live
// entirely in registers (128 VGPR); B-fragments gathered direct from embB.
// No LDS, no barriers. h scattered to Hagg[g][node][128] via packed bf16
// atomics (2 vals/op): linearity lets W2 be applied after aggregation.

__global__ __launch_bounds__(256, 2) void edge_h_k(
    const bf16* __restrict__ embB,
    const int* __restrict__ a0, const int* __restrict__ a1,
    const int* __restrict__ a2, const int* __restrict__ a3,
    const bf16* __restrict__ w1t,
    bf16* __restrict__ Hagg) {

  const int tid  = threadIdx.x;
  const int w    = tid >> 6;
  const int lane = tid & 63;
  const int dh = w & 1, ep = w >> 1;       // dims-half, epoch
  const int l  = blockIdx.x / 400;         // layer
  const int bl = blockIdx.x % 400;         // 400 blocks/layer, 400 edges each
  const int g  = l * 2 + ep;
  const int* __restrict__ adj = (l == 0) ? a0 : (l == 1) ? a1 : (l == 2) ? a2 : a3;
  const int l15 = lane & 15, q = lane >> 4;

  // ---- preload W1^T A-fragments into registers: 4 m-blocks x 8 k-blocks ----
  // A[m=16*mb+l15][k=kb*32+q*8+j], rows offset by g*128 + dh*64
  bf16x8 wA[4][8];
  const bf16* w1row = w1t + ((size_t)(g * 128 + dh * 64)) * 256;
  #pragma unroll
  for (int mb = 0; mb < 4; ++mb)
    #pragma unroll
    for (int kb = 0; kb < 8; ++kb)
      wA[mb][kb] = *(const bf16x8*)(w1row + (mb * 16 + l15) * 256 + kb * 32 + q * 8);

  bf16* __restrict__ HaggG = Hagg + (size_t)g * V_NODES * 128 + dh * 64;

  for (int t = 0; t < 25; ++t) {
    const int e = bl * 400 + t * 16 + l15;       // this lane's edge
    int2 pr = ((const int2*)adj)[e];
    const int src = clampV(pr.x), dst = clampV(pr.y);
    const int tgt = ep ? dst : src;

    // B-fragments: raw^T[k][e], lane (q,l15): 16B from emb row at k=kb*32+q*8
    bf16x8 b[8];
    #pragma unroll
    for (int kb = 0; kb < 8; ++kb) {
      const int node = (kb < 4) ? src : dst;
      const int klo = (kb * 32 + q * 8) & 127;
      b[kb] = *(const bf16x8*)(embB + (size_t)node * 128 + klo);
    }

    // D[m=hidden][n=edge]: acc[mb][r] = h[16*mb + q*4 + r (+64*dh)] of edge l15
    f32x4 acc[4] = {};
    #pragma unroll
    for (int kb = 0; kb < 8; ++kb)
      #pragma unroll
      for (int mb = 0; mb < 4; ++mb)
        acc[mb] = __builtin_amdgcn_mfma_f32_16x16x32_bf16(wA[mb][kb], b[kb], acc[mb], 0, 0, 0);

    // relu + packed-bf16 scatter: dims {16mb + q*4 + 2p, +1} of this edge
    bf16* basep = HaggG + (size_t)tgt * 128 + q * 4;
    #pragma unroll
    for (int mb = 0; mb < 4; ++mb)
      #pragma unroll
      for (int p = 0; p < 2; ++p) {
        float lo = fmaxf(acc[mb][2 * p], 0.f);
        float hi = fmaxf(acc[mb][2 * p + 1], 0.f);
        pk_atomic_bf16(basep + mb * 16 + 2 * p, lo, hi);
      }
  }
}

// ---------------- final dense GEMM: out = relu(sum_g Hagg_g @ W2_g) --------
// 64 rows/block (4 waves x 16), full 128 cols/wave, K = 8 groups x 128.

__global__ __launch_bounds__(256) void gemm2_k(const bf16* __restrict__ Hagg,
                                               const bf16* __restrict__ w2t,
                                               float* __restrict__ out) {
  const int tid = threadIdx.x, wv = tid >> 6, lane = tid & 63;
  const int l15 = lane & 15, q = lane >> 4;
  const int v0 = blockIdx.x * 64;
  const int vr = v0 + wv * 16 + l15;
  const int vc = vr < V_NODES ? vr : V_NODES - 1;   // clamp loads, mask stores

  f32x4 acc[8] = {};
  for (int g = 0; g < 8; ++g) {
    const bf16* Ha = Hagg + ((size_t)g * V_NODES + vc) * 128;
    const bf16* Wb = w2t + (size_t)g * 128 * 128;
    #pragma unroll
    for (int kb = 0; kb < 4; ++kb) {
      bf16x8 a = *(const bf16x8*)(Ha + kb * 32 + q * 8);
      #pragma unroll
      for (int nb = 0; nb < 8; ++nb) {
        bf16x8 b = *(const bf16x8*)(Wb + (nb * 16 + l15) * 128 + kb * 32 + q * 8);
        acc[nb] = __builtin_amdgcn_mfma_f32_16x16x32_bf16(a, b, acc[nb], 0, 0, 0);
      }
    }
  }

  const int row = v0 + wv * 16 + q * 4;
  #pragma unroll
  for (int r = 0; r < 4; ++r) {
    if (row + r < V_NODES) {
      #pragma unroll
      for (int nb = 0; nb < 8; ++nb)
        out[(size_t)(row + r) * 128 + nb * 16 + l15] = fmaxf(acc[nb][r], 0.f);
    }
  }
}

// ---------------- fallback edge kernel (round-4, proven) -------------------

__global__ __launch_bounds__(256) void edge_k(
    const bf16* __restrict__ embB,
    const int* __restrict__ a0, const int* __restrict__ a1,
    const int* __restrict__ a2, const int* __restrict__ a3,
    const bf16* __restrict__ w1t, const bf16* __restrict__ w2t,
    float* __restrict__ out) {

  __shared__ __attribute__((aligned(16))) bf16 w1_lds[128 * 256];
  __shared__ __attribute__((aligned(16))) bf16 h_lds[64 * 128];

  const int tid = threadIdx.x;
  const int g  = blockIdx.x >> 6;
  const int bs = blockIdx.x & 63;
  const int l = g >> 1, ep = g & 1;
  const int* __restrict__ adj = (l == 0) ? a0 : (l == 1) ? a1 : (l == 2) ? a2 : a3;

  {
    const uint4* w1g = (const uint4*)(w1t + (size_t)g * 128 * 256);
    #pragma unroll
    for (int i = 0; i < 16; ++i) {
      int j = i * 256 + tid;
      int n = j >> 5, c = j & 31;
      *(uint4*)(&w1_lds[n * 256 + ((c ^ (n & 7)) << 3)]) = w1g[j];
    }
  }
  __syncthreads();

  const int w    = tid >> 6;
  const int lane = tid & 63;
  const int wr = w >> 1, wc = w & 1;
  const int l15 = lane & 15, q = lane >> 4;
  const bf16* __restrict__ w2g = w2t + (size_t)g * 128 * 128;

  for (int t = bs; t < 2500; t += 64) {
    const int ebase = t * 64;
    int2 pr0 = ((const int2*)adj)[ebase + 32 * wr + l15];
    int2 pr1 = ((const int2*)adj)[ebase + 32 * wr + 16 + l15];
    pr0.x = clampV(pr0.x); pr0.y = clampV(pr0.y);
    pr1.x = clampV(pr1.x); pr1.y = clampV(pr1.y);

    f32x4 acc[2][4] = {};
    #pragma unroll
    for (int kb = 0; kb < 8; ++kb) {
      const int k = kb * 32 + q * 8;
      const int klo = k & 127;
      const int n0 = (kb < 4) ? pr0.x : pr0.y;
      const int n1 = (kb < 4) ? pr1.x : pr1.y;
      bf16x8 a[2], b[4];
      a[0] = *(const bf16x8*)(embB + (size_t)n0 * 128 + klo);
      a[1] = *(const bf16x8*)(embB + (size_t)n1 * 128 + klo);
      const int csw = ((kb << 2) + q);
      #pragma unroll
      for (int nt = 0; nt < 4; ++nt) {
        int n = 64 * wc + 16 * nt + l15;
        b[nt] = *(const bf16x8*)(&w1_lds[n * 256 + ((csw ^ (l15 & 7)) << 3)]);
      }
      #pragma unroll
      for (int mt = 0; mt < 2; ++mt)
        #pragma unroll
        for (int nt = 0; nt < 4; ++nt)
          acc[mt][nt] = __builtin_amdgcn_mfma_f32_16x16x32_bf16(a[mt], b[nt], acc[mt][nt], 0, 0, 0);
    }

    __syncthreads();
    #pragma unroll
    for (int mt = 0; mt < 2; ++mt)
      #pragma unroll
      for (int nt = 0; nt < 4; ++nt)
        #pragma unroll
        for (int r = 0; r < 4; ++r) {
          float v = acc[mt][nt][r];
          v = v > 0.f ? v : 0.f;
          int row = 32 * wr + 16 * mt + 4 * q + r;
          int col = 64 * wc + 16 * nt + l15;
          int c = col >> 3;
          h_lds[row * 128 + (((c ^ (row & 7)) << 3) | (col & 7))] = (bf16)v;
        }
    __syncthreads();

    f32x4 acc2[2][4] = {};
    #pragma unroll
    for (int kb = 0; kb < 4; ++kb) {
      const int k = kb * 32 + q * 8;
      const int csw = (kb << 2) + q;
      bf16x8 a[2], b[4];
      #pragma unroll
      for (int mt = 0; mt < 2; ++mt) {
        int row = 32 * wr + 16 * mt + l15;
        a[mt] = *(const bf16x8*)(&h_lds[row * 128 + ((csw ^ (row & 7)) << 3)]);
      }
      #pragma unroll
      for (int nt = 0; nt < 4; ++nt) {
        int n = 64 * wc + 16 * nt + l15;
        b[nt] = *(const bf16x8*)(w2g + n * 128 + k);
      }
      #pragma unroll
      for (int mt = 0; mt < 2; ++mt)
        #pragma unroll
        for (int nt = 0; nt < 4; ++nt)
          acc2[mt][nt] = __builtin_amdgcn_mfma_f32_16x16x32_bf16(a[mt], b[nt], acc2[mt][nt], 0, 0, 0);
    }

    #pragma unroll
    for (int mt = 0; mt < 2; ++mt)
      #pragma unroll
      for (int r = 0; r < 4; ++r) {
        int row = 32 * wr + 16 * mt + 4 * q + r;
        int2 pr = ((const int2*)adj)[ebase + row];
        int node = clampV(ep ? pr.y : pr.x);
        float* basep = out + (size_t)node * 128 + 64 * wc + l15;
        #pragma unroll
        for (int nt = 0; nt < 4; ++nt)
          unsafeAtomicAdd(basep + 16 * nt, acc2[mt][nt][r]);
      }
  }
}

// ---------------- host launch ----------------------------------------------

extern "C" void kernel_launch(void* const* d_in, const int* in_sizes, int n_in,
                              void* d_out, int out_size, void* d_ws, size_t ws_size,
                              hipStream_t stream) {
  const float* emb = (const float*)d_in[0];
  const int* a0 = (const int*)d_in[1];
  const int* a1 = (const int*)d_in[2];
  const int* a2 = (const int*)d_in[3];
  const int* a3 = (const int*)d_in[4];
  const float* W1 = (const float*)d_in[5];
  const float* W2 = (const float*)d_in[6];
  float* out = (float*)d_out;

  char* ws = (char*)d_ws;
  bf16* embB = (bf16*)ws;                      // 12,800,000 B
  bf16* w1t  = (bf16*)(ws + 12800000);         //    524,288 B
  bf16* w2t  = (bf16*)(ws + 13324288);         //    262,144 B
  bf16* Hagg = (bf16*)(ws + 13586432);         // 102,400,000 B (main path)
  const size_t need = 13586432 + (size_t)8 * V_NODES * 128 * 2;

  prep_emb_k<<<6250, 256, 0, stream>>>(emb, embB);
  prep_w1_k<<<1024, 256, 0, stream>>>(W1, w1t);
  prep_w2_k<<<512, 256, 0, stream>>>(W2, w2t);

  if (ws_size >= need) {
    hipMemsetAsync(Hagg, 0, (size_t)8 * V_NODES * 128 * 2, stream);
    edge_h_k<<<1600, 256, 0, stream>>>(embB, a0, a1, a2, a3, w1t, Hagg);
    gemm2_k<<<782, 256, 0, stream>>>(Hagg, w2t, out);
  } else {
    hipMemsetAsync(d_out, 0, (size_t)V_NODES * 128 * sizeof(float), stream);
    edge_k<<<512, 256, 0, stream>>>(embB, a0, a1, a2, a3, w1t, w2t, out);
    relu_k<<<6250, 256, 0, stream>>>(out);
  }
}

// Round 6
// 636.722 us; speedup vs baseline: 2.1087x; 2.1087x over previous
//
#include <hip/hip_runtime.h>

// (V, D, H, L, E) = (50000, 128, 128, 4, 160000)
#define V_NODES 50000
#define NEDGE   160000
#define NSEG    (8 * V_NODES)          // 400000 (g,node) segments

typedef __bf16 bf16;
typedef __attribute__((ext_vector_type(8))) __bf16 bf16x8;
typedef __attribute__((ext_vector_type(4))) __bf16 bf16x4;
typedef __attribute__((ext_vector_type(4))) float  f32x4;

__device__ __forceinline__ int clampV(int n) {
  unsigned u = (unsigned)n;
  return (int)(u < (unsigned)V_NODES ? u : (unsigned)(V_NODES - 1));
}

// ---------------- prep kernels: fp32 -> bf16 (weights transposed) ----------

__global__ __launch_bounds__(256) void prep_emb_k(const float* __restrict__ in,
                                                  bf16* __restrict__ out) {
  int i = blockIdx.x * 256 + threadIdx.x;
  float4 v = ((const float4*)in)[i];
  bf16x4 o = {(bf16)v.x, (bf16)v.y, (bf16)v.z, (bf16)v.w};
  *(bf16x4*)(out + (size_t)i * 4) = o;
}

__global__ __launch_bounds__(256) void prep_w1_k(const float* __restrict__ in,
                                                 bf16* __restrict__ out) {
  int idx = blockIdx.x * 256 + threadIdx.x;         // 262144
  int n = idx & 127, k = (idx >> 7) & 255, g = idx >> 15;
  out[(((g << 7) + n) << 8) + k] = (bf16)in[idx];
}

__global__ __launch_bounds__(256) void prep_w2_k(const float* __restrict__ in,
                                                 bf16* __restrict__ out) {
  int idx = blockIdx.x * 256 + threadIdx.x;         // 131072
  int n = idx & 127, k = (idx >> 7) & 127, g = idx >> 14;
  out[(((g << 7) + n) << 7) + k] = (bf16)in[idx];
}

__global__ __launch_bounds__(256) void relu_k(float* __restrict__ out) {
  int i = blockIdx.x * 256 + threadIdx.x;
  float4 v = ((float4*)out)[i];
  v.x = fmaxf(v.x, 0.f); v.y = fmaxf(v.y, 0.f);
  v.z = fmaxf(v.z, 0.f); v.w = fmaxf(v.w, 0.f);
  ((float4*)out)[i] = v;
}

// ---------------- CSR build ------------------------------------------------

__global__ __launch_bounds__(256) void hist_k(
    const int* __restrict__ a0, const int* __restrict__ a1,
    const int* __restrict__ a2, const int* __restrict__ a3,
    int* __restrict__ counts) {
  int e = blockIdx.x * 256 + threadIdx.x;    // 0..159999
  int g = blockIdx.y;                        // 0..7
  int l = g >> 1, ep = g & 1;
  const int* adj = (l == 0) ? a0 : (l == 1) ? a1 : (l == 2) ? a2 : a3;
  int tgt = clampV(adj[2 * e + ep]);
  atomicAdd(&counts[g * V_NODES + tgt], 1);
}

// scan_a: 512 elems/block, exclusive within block, emit block sums
__global__ __launch_bounds__(256) void scan_a_k(const int* __restrict__ counts,
                                                int* __restrict__ offs,
                                                int* __restrict__ bsums) {
  __shared__ int sh[256];
  int t = threadIdx.x, base = blockIdx.x * 512;
  int e0 = base + 2 * t, e1 = e0 + 1;
  int a = (e0 < NSEG) ? counts[e0] : 0;
  int b = (e1 < NSEG) ? counts[e1] : 0;
  int s = a + b;
  sh[t] = s;
  __syncthreads();
  // Hillis-Steele inclusive scan over 256
  #pragma unroll
  for (int d = 1; d < 256; d <<= 1) {
    int v = (t >= d) ? sh[t - d] : 0;
    __syncthreads();
    sh[t] += v;
    __syncthreads();
  }
  int excl = sh[t] - s;
  if (e0 < NSEG) offs[e0] = excl;
  if (e1 < NSEG) offs[e1] = excl + a;
  if (t == 255) bsums[blockIdx.x] = sh[255];
}

#define NBLK_SCAN 782   // ceil(400000/512)

__global__ __launch_bounds__(256) void scan_b_k(int* __restrict__ bsums,
                                                int* __restrict__ offs) {
  __shared__ int sh[NBLK_SCAN];
  int t = threadIdx.x;
  for (int i = t; i < NBLK_SCAN; i += 256) sh[i] = bsums[i];
  __syncthreads();
  if (t == 0) {
    int run = 0;
    for (int i = 0; i < NBLK_SCAN; ++i) { int v = sh[i]; sh[i] = run; run += v; }
    offs[NSEG] = run;        // total
  }
  __syncthreads();
  for (int i = t; i < NBLK_SCAN; i += 256) bsums[i] = sh[i];
}

__global__ __launch_bounds__(256) void scan_c_k(int* __restrict__ offs,
                                                const int* __restrict__ bsums) {
  int i = blockIdx.x * 256 + threadIdx.x;
  if (i < NSEG) offs[i] += bsums[i >> 9];
}

__global__ __launch_bounds__(256) void scatter_ids_k(
    const int* __restrict__ a0, const int* __restrict__ a1,
    const int* __restrict__ a2, const int* __restrict__ a3,
    const int* __restrict__ offs, int* __restrict__ cursor,
    int* __restrict__ ids) {
  int e = blockIdx.x * 256 + threadIdx.x;
  int g = blockIdx.y;
  int l = g >> 1, ep = g & 1;
  const int* adj = (l == 0) ? a0 : (l == 1) ? a1 : (l == 2) ? a2 : a3;
  int seg = g * V_NODES + clampV(adj[2 * e + ep]);
  int pos = offs[seg] + atomicAdd(&cursor[seg], 1);
  ids[pos] = e;
}

// ---------------- edge kernel: h -> hbuf (no atomics) ----------------------
// Round-5 structure: wave = (ep = w>>1, dh = w&1), 16 edges/lane-tile,
// W1^T A-frags register-resident (128 VGPR), B gathered from embB.
// Output: relu(h) packed bf16x4 -> hbuf[g][e][128], plain stores.

__global__ __launch_bounds__(256, 2) void edge_h2_k(
    const bf16* __restrict__ embB,
    const int* __restrict__ a0, const int* __restrict__ a1,
    const int* __restrict__ a2, const int* __restrict__ a3,
    const bf16* __restrict__ w1t,
    bf16* __restrict__ hbuf) {

  const int tid  = threadIdx.x;
  const int w    = tid >> 6;
  const int lane = tid & 63;
  const int dh = w & 1, ep = w >> 1;
  const int l  = blockIdx.y;               // layer
  const int bl = blockIdx.x;               // 400 blocks/layer, 400 edges each
  const int g  = l * 2 + ep;
  const int* __restrict__ adj = (l == 0) ? a0 : (l == 1) ? a1 : (l == 2) ? a2 : a3;
  const int l15 = lane & 15, q = lane >> 4;

  bf16x8 wA[4][8];
  const bf16* w1row = w1t + ((size_t)(g * 128 + dh * 64)) * 256;
  #pragma unroll
  for (int mb = 0; mb < 4; ++mb)
    #pragma unroll
    for (int kb = 0; kb < 8; ++kb)
      wA[mb][kb] = *(const bf16x8*)(w1row + (mb * 16 + l15) * 256 + kb * 32 + q * 8);

  bf16* __restrict__ hG = hbuf + (size_t)g * NEDGE * 128 + dh * 64;

  for (int t = 0; t < 25; ++t) {
    const int e = bl * 400 + t * 16 + l15;
    int2 pr = ((const int2*)adj)[e];
    const int src = clampV(pr.x), dst = clampV(pr.y);

    bf16x8 b[8];
    #pragma unroll
    for (int kb = 0; kb < 8; ++kb) {
      const int node = (kb < 4) ? src : dst;
      const int klo = (kb * 32 + q * 8) & 127;
      b[kb] = *(const bf16x8*)(embB + (size_t)node * 128 + klo);
    }

    f32x4 acc[4] = {};
    #pragma unroll
    for (int kb = 0; kb < 8; ++kb)
      #pragma unroll
      for (int mb = 0; mb < 4; ++mb)
        acc[mb] = __builtin_amdgcn_mfma_f32_16x16x32_bf16(wA[mb][kb], b[kb], acc[mb], 0, 0, 0);

    // relu + pack 4 consecutive dims (16mb+4q+0..3) -> one 8B store each
    bf16* basep = hG + (size_t)e * 128 + q * 4;
    #pragma unroll
    for (int mb = 0; mb < 4; ++mb) {
      bf16x4 o = {(bf16)fmaxf(acc[mb][0], 0.f), (bf16)fmaxf(acc[mb][1], 0.f),
                  (bf16)fmaxf(acc[mb][2], 0.f), (bf16)fmaxf(acc[mb][3], 0.f)};
      *(bf16x4*)(basep + mb * 16) = o;
    }
  }
}

// ---------------- aggregate: Hagg[g][node] = sum of hbuf rows --------------
// One wave per (g,node) segment; 64 lanes x bf16x2 = full 256B row.

__global__ __launch_bounds__(256) void agg_k(const bf16* __restrict__ hbuf,
                                             const int* __restrict__ offs,
                                             const int* __restrict__ ids,
                                             bf16* __restrict__ Hagg) {
  const int wv = threadIdx.x >> 6, lane = threadIdx.x & 63;
  const int node = blockIdx.x * 4 + wv;
  const int g = blockIdx.y;
  const int seg = g * V_NODES + node;
  const int beg = offs[seg], end = offs[seg + 1];

  const bf16* hG = hbuf + (size_t)g * NEDGE * 128;
  float sx = 0.f, sy = 0.f;
  for (int i = beg; i < end; ++i) {
    int e = ids[i];
    unsigned u = *(const unsigned*)(hG + (size_t)e * 128 + lane * 2);
    unsigned short ulo = (unsigned short)u, uhi = (unsigned short)(u >> 16);
    sx += (float)__builtin_bit_cast(bf16, ulo);
    sy += (float)__builtin_bit_cast(bf16, uhi);
  }
  bf16 plo = (bf16)sx, phi = (bf16)sy;
  unsigned pu = (unsigned)__builtin_bit_cast(unsigned short, plo)
              | ((unsigned)__builtin_bit_cast(unsigned short, phi) << 16);
  *(unsigned*)(Hagg + ((size_t)g * V_NODES + node) * 128 + lane * 2) = pu;
}

// ---------------- final dense GEMM: out = relu(sum_g Hagg_g @ W2_g) --------

__global__ __launch_bounds__(256) void gemm2_k(const bf16* __restrict__ Hagg,
                                               const bf16* __restrict__ w2t,
                                               float* __restrict__ out) {
  const int tid = threadIdx.x, wv = tid >> 6, lane = tid & 63;
  const int l15 = lane & 15, q = lane >> 4;
  const int v0 = blockIdx.x * 64;
  const int vr = v0 + wv * 16 + l15;
  const int vc = vr < V_NODES ? vr : V_NODES - 1;

  f32x4 acc[8] = {};
  for (int g = 0; g < 8; ++g) {
    const bf16* Ha = Hagg + ((size_t)g * V_NODES + vc) * 128;
    const bf16* Wb = w2t + (size_t)g * 128 * 128;
    #pragma unroll
    for (int kb = 0; kb < 4; ++kb) {
      bf16x8 a = *(const bf16x8*)(Ha + kb * 32 + q * 8);
      #pragma unroll
      for (int nb = 0; nb < 8; ++nb) {
        bf16x8 b = *(const bf16x8*)(Wb + (nb * 16 + l15) * 128 + kb * 32 + q * 8);
        acc[nb] = __builtin_amdgcn_mfma_f32_16x16x32_bf16(a, b, acc[nb], 0, 0, 0);
      }
    }
  }

  const int row = v0 + wv * 16 + q * 4;
  #pragma unroll
  for (int r = 0; r < 4; ++r) {
    if (row + r < V_NODES) {
      #pragma unroll
      for (int nb = 0; nb < 8; ++nb)
        out[(size_t)(row + r) * 128 + nb * 16 + l15] = fmaxf(acc[nb][r], 0.f);
    }
  }
}

// ---------------- fallback edge kernel (round-4, proven) -------------------

__global__ __launch_bounds__(256) void edge_k(
    const bf16* __restrict__ embB,
    const int* __restrict__ a0, const int* __restrict__ a1,
    const int* __restrict__ a2, const int* __restrict__ a3,
    const bf16* __restrict__ w1t, const bf16* __restrict__ w2t,
    float* __restrict__ out) {

  __shared__ __attribute__((aligned(16))) bf16 w1_lds[128 * 256];
  __shared__ __attribute__((aligned(16))) bf16 h_lds[64 * 128];

  const int tid = threadIdx.x;
  const int g  = blockIdx.x >> 6;
  const int bs = blockIdx.x & 63;
  const int l = g >> 1, ep = g & 1;
  const int* __restrict__ adj = (l == 0) ? a0 : (l == 1) ? a1 : (l == 2) ? a2 : a3;

  {
    const uint4* w1g = (const uint4*)(w1t + (size_t)g * 128 * 256);
    #pragma unroll
    for (int i = 0; i < 16; ++i) {
      int j = i * 256 + tid;
      int n = j >> 5, c = j & 31;
      *(uint4*)(&w1_lds[n * 256 + ((c ^ (n & 7)) << 3)]) = w1g[j];
    }
  }
  __syncthreads();

  const int w    = tid >> 6;
  const int lane = tid & 63;
  const int wr = w >> 1, wc = w & 1;
  const int l15 = lane & 15, q = lane >> 4;
  const bf16* __restrict__ w2g = w2t + (size_t)g * 128 * 128;

  for (int t = bs; t < 2500; t += 64) {
    const int ebase = t * 64;
    int2 pr0 = ((const int2*)adj)[ebase + 32 * wr + l15];
    int2 pr1 = ((const int2*)adj)[ebase + 32 * wr + 16 + l15];
    pr0.x = clampV(pr0.x); pr0.y = clampV(pr0.y);
    pr1.x = clampV(pr1.x); pr1.y = clampV(pr1.y);

    f32x4 acc[2][4] = {};
    #pragma unroll
    for (int kb = 0; kb < 8; ++kb) {
      const int k = kb * 32 + q * 8;
      const int klo = k & 127;
      const int n0 = (kb < 4) ? pr0.x : pr0.y;
      const int n1 = (kb < 4) ? pr1.x : pr1.y;
      bf16x8 a[2], b[4];
      a[0] = *(const bf16x8*)(embB + (size_t)n0 * 128 + klo);
      a[1] = *(const bf16x8*)(embB + (size_t)n1 * 128 + klo);
      const int csw = ((kb << 2) + q);
      #pragma unroll
      for (int nt = 0; nt < 4; ++nt) {
        int n = 64 * wc + 16 * nt + l15;
        b[nt] = *(const bf16x8*)(&w1_lds[n * 256 + ((csw ^ (l15 & 7)) << 3)]);
      }
      #pragma unroll
      for (int mt = 0; mt < 2; ++mt)
        #pragma unroll
        for (int nt = 0; nt < 4; ++nt)
          acc[mt][nt] = __builtin_amdgcn_mfma_f32_16x16x32_bf16(a[mt], b[nt], acc[mt][nt], 0, 0, 0);
    }

    __syncthreads();
    #pragma unroll
    for (int mt = 0; mt < 2; ++mt)
      #pragma unroll
      for (int nt = 0; nt < 4; ++nt)
        #pragma unroll
        for (int r = 0; r < 4; ++r) {
          float v = acc[mt][nt][r];
          v = v > 0.f ? v : 0.f;
          int row = 32 * wr + 16 * mt + 4 * q + r;
          int col = 64 * wc + 16 * nt + l15;
          int c = col >> 3;
          h_lds[row * 128 + (((c ^ (row & 7)) << 3) | (col & 7))] = (bf16)v;
        }
    __syncthreads();

    f32x4 acc2[2][4] = {};
    #pragma unroll
    for (int kb = 0; kb < 4; ++kb) {
      const int k = kb * 32 + q * 8;
      const int csw = (kb << 2) + q;
      bf16x8 a[2], b[4];
      #pragma unroll
      for (int mt = 0; mt < 2; ++mt) {
        int row = 32 * wr + 16 * mt + l15;
        a[mt] = *(const bf16x8*)(&h_lds[row * 128 + ((csw ^ (row & 7)) << 3)]);
      }
      #pragma unroll
      for (int nt = 0; nt < 4; ++nt) {
        int n = 64 * wc + 16 * nt + l15;
        b[nt] = *(const bf16x8*)(w2g + n * 128 + k);
      }
      #pragma unroll
      for (int mt = 0; mt < 2; ++mt)
        #pragma unroll
        for (int nt = 0; nt < 4; ++nt)
          acc2[mt][nt] = __builtin_amdgcn_mfma_f32_16x16x32_bf16(a[mt], b[nt], acc2[mt][nt], 0, 0, 0);
    }

    #pragma unroll
    for (int mt = 0; mt < 2; ++mt)
      #pragma unroll
      for (int r = 0; r < 4; ++r) {
        int row = 32 * wr + 16 * mt + 4 * q + r;
        int2 pr = ((const int2*)adj)[ebase + row];
        int node = clampV(ep ? pr.y : pr.x);
        float* basep = out + (size_t)node * 128 + 64 * wc + l15;
        #pragma unroll
        for (int nt = 0; nt < 4; ++nt)
          unsafeAtomicAdd(basep + 16 * nt, acc2[mt][nt][r]);
      }
  }
}

// ---------------- host launch ----------------------------------------------

extern "C" void kernel_launch(void* const* d_in, const int* in_sizes, int n_in,
                              void* d_out, int out_size, void* d_ws, size_t ws_size,
                              hipStream_t stream) {
  const float* emb = (const float*)d_in[0];
  const int* a0 = (const int*)d_in[1];
  const int* a1 = (const int*)d_in[2];
  const int* a2 = (const int*)d_in[3];
  const int* a3 = (const int*)d_in[4];
  const float* W1 = (const float*)d_in[5];
  const float* W2 = (const float*)d_in[6];
  float* out = (float*)d_out;

  char* ws = (char*)d_ws;
  bf16* embB   = (bf16*)(ws);                    // 12,800,000
  bf16* w1t    = (bf16*)(ws + 12800000);         //    524,288
  bf16* w2t    = (bf16*)(ws + 13324288);         //    262,144
  int*  counts = (int*) (ws + 13586432);         //  1,600,000
  int*  cursor = (int*) (ws + 15186432);         //  1,600,000
  int*  offs   = (int*) (ws + 16786432);         //  1,600,256 (400001 ints)
  int*  bsums  = (int*) (ws + 18386688);         //      8,192
  int*  ids    = (int*) (ws + 18394880);         //  5,120,000
  bf16* Hagg   = (bf16*)(ws + 23514880);         // 102,400,000
  bf16* hbuf   = (bf16*)(ws + 125914880);        // 327,680,000
  const size_t need_full = 453594880;

  prep_emb_k<<<6250, 256, 0, stream>>>(emb, embB);
  prep_w1_k<<<1024, 256, 0, stream>>>(W1, w1t);
  prep_w2_k<<<512, 256, 0, stream>>>(W2, w2t);

  if (ws_size >= need_full) {
    hipMemsetAsync(counts, 0, 3200000, stream);   // counts + cursor
    hist_k<<<dim3(625, 8), 256, 0, stream>>>(a0, a1, a2, a3, counts);
    scan_a_k<<<NBLK_SCAN, 256, 0, stream>>>(counts, offs, bsums);
    scan_b_k<<<1, 256, 0, stream>>>(bsums, offs);
    scan_c_k<<<1563, 256, 0, stream>>>(offs, bsums);
    scatter_ids_k<<<dim3(625, 8), 256, 0, stream>>>(a0, a1, a2, a3, offs, cursor, ids);
    edge_h2_k<<<dim3(400, 4), 256, 0, stream>>>(embB, a0, a1, a2, a3, w1t, hbuf);
    agg_k<<<dim3(12500, 8), 256, 0, stream>>>(hbuf, offs, ids, Hagg);
    gemm2_k<<<782, 256, 0, stream>>>(Hagg, w2t, out);
  } else {
    hipMemsetAsync(d_out, 0, (size_t)V_NODES * 128 * sizeof(float), stream);
    edge_k<<<512, 256, 0, stream>>>(embB, a0, a1, a2, a3, w1t, w2t, out);
    relu_k<<<6250, 256, 0, stream>>>(out);
  }
}